// Round 1
// baseline (95.556 us; speedup 1.0000x reference)
//
#include <hip/hip_runtime.h>

#define N_NODES 32768
#define NB 128           // histogram blocks (256 nodes each)
#define DIM 128
#define NT 17
#define ROWS 64
#define BPT 48           // blocks per type: capacity 3072 rows/type (mean 1928, sigma 43)
#define CAP (BPT * ROWS) // 3072 slots per type in rows[]
#define LP 136           // LDS row pitch in ushorts (272B: conflict-free b128 frag reads)

typedef short bf16x8 __attribute__((ext_vector_type(8)));
typedef float f32x4 __attribute__((ext_vector_type(4)));

// ws layout (bytes) — slot reservation via global atomics; row order within a
// type is nondeterministic but output is order-invariant (each row depends
// only on its own node), so results stay deterministic.
#define WS_CNT   0        // 17 int, memset to 0 each launch
#define WS_ROWS  256      // 17*3072 ushort = 104448 -> ends 104704
#define WS_W1T   104704   // 17*128*128 ushort (bf16, [t][n][k]) = 557056 -> 661760
#define WS_W2T   661760   // same -> ends 1218816

__device__ __forceinline__ unsigned short f2bf(float f) {
  unsigned int u = __float_as_uint(f);
  u += 0x7FFFu + ((u >> 16) & 1u);   // RTNE
  return (unsigned short)(u >> 16);
}

// blocks 0..127: per-block histogram (LDS atomics) + direct compaction:
//   block reserves h[t] contiguous slots in type t's region via one global
//   atomicAdd, then scatters its node indices there. No scan, no tl array.
// blocks 128..161: convert W1/W2 fp32 [t][k][n] -> bf16 [t][n][k].
__global__ void k_pre(const int* __restrict__ types, int* __restrict__ cnt,
                      unsigned short* __restrict__ rows,
                      const float* __restrict__ W1, const float* __restrict__ W2,
                      unsigned short* __restrict__ W1t, unsigned short* __restrict__ W2t) {
  int tid = threadIdx.x;
  if (blockIdx.x < NB) {
    __shared__ int h[NT];
    __shared__ int bb[NT];
    if (tid < NT) h[tid] = 0;
    __syncthreads();
    int i = blockIdx.x * 256 + tid;
    int ty = types[i];
    int r = atomicAdd(&h[ty], 1);            // LDS atomic: fast, gives local rank
    __syncthreads();
    if (tid < NT) bb[tid] = atomicAdd(&cnt[tid], h[tid]);  // reserve slot range
    __syncthreads();
    rows[ty * CAP + bb[ty] + r] = (unsigned short)i;
    return;
  }
  int m = blockIdx.x - NB;  // 0..33
  const float* src = (m < NT) ? (W1 + (size_t)m * DIM * DIM)
                              : (W2 + (size_t)(m - NT) * DIM * DIM);
  unsigned short* dst = (m < NT) ? (W1t + (size_t)m * DIM * DIM)
                                 : (W2t + (size_t)(m - NT) * DIM * DIM);
  __shared__ unsigned short tile[DIM * LP];
  #pragma unroll
  for (int it = 0; it < 32; ++it) {
    int s = tid + it * 256;            // 0..8191
    int n = s & 127, kp = s >> 7;      // kp: 0..63
    float a = src[(size_t)(2 * kp) * DIM + n];
    float b = src[(size_t)(2 * kp + 1) * DIM + n];
    unsigned int pk = (unsigned int)f2bf(a) | ((unsigned int)f2bf(b) << 16);
    *(unsigned int*)&tile[n * LP + 2 * kp] = pk;
  }
  __syncthreads();
  #pragma unroll
  for (int it = 0; it < 8; ++it) {
    int s = tid + it * 256;            // 0..2047
    int n = s >> 4, c = s & 15;
    *(uint4*)(dst + (size_t)n * DIM + c * 8) = *(const uint4*)&tile[n * LP + c * 8];
  }
}

__global__ __launch_bounds__(256, 3)
void k_mlp(const float* __restrict__ x, const float* __restrict__ b1,
           const float* __restrict__ b2, float* __restrict__ out,
           const int* __restrict__ cnt, const unsigned short* __restrict__ rows,
           const unsigned short* __restrict__ W1t, const unsigned short* __restrict__ W2t) {
  int t = blockIdx.y;
  int tid = threadIdx.x;

  // ---- prologue: 1 load, free early-exit, direct coalesced row-index load ----
  int total = cnt[t];                  // visible: kernel-boundary coherence
  int win_lo = blockIdx.x * ROWS;
  if (win_lo >= total) return;         // block-uniform early exit, pre-barrier
  int nvalid = min(ROWS, total - win_lo);

  __shared__ int prow[ROWS];
  __shared__ unsigned short Xs[ROWS * LP];   // doubles as H buffer (wave-private rows)
  __shared__ unsigned short Ws[DIM * LP];

  if (tid < ROWS)
    prow[tid] = rows[t * CAP + win_lo + min(tid, nvalid - 1)];  // pad w/ last valid
  __syncthreads();

  // ---- stage X: gather rows (512B contiguous each), fp32 -> bf16 ----
  #pragma unroll
  for (int it = 0; it < 8; ++it) {
    int s = tid + it * 256;            // 0..2047
    int r = s >> 5, c4 = s & 31;
    const float4 vx = *(const float4*)(x + (size_t)prow[r] * DIM + c4 * 4);
    unsigned int lo2 = (unsigned int)f2bf(vx.x) | ((unsigned int)f2bf(vx.y) << 16);
    unsigned int hi2 = (unsigned int)f2bf(vx.z) | ((unsigned int)f2bf(vx.w) << 16);
    *(uint2*)&Xs[r * LP + c4 * 4] = make_uint2(lo2, hi2);
  }
  // stage W1 (pre-transposed bf16): 16B/lane copy
  const unsigned short* w1g = W1t + (size_t)t * DIM * DIM;
  #pragma unroll
  for (int it = 0; it < 8; ++it) {
    int s = tid + it * 256;
    int n = s >> 4, c = s & 15;
    *(uint4*)&Ws[n * LP + c * 8] = *(const uint4*)(w1g + n * DIM + c * 8);
  }
  __syncthreads();

  int lane = tid & 63, w = tid >> 6;
  int l15 = lane & 15, q = lane >> 4;
  int arow = w * 16 + l15;
  int kb = q * 8;

  // ---- layer 1: H = relu(X*W1 + b1) ----
  f32x4 acc[8];
  #pragma unroll
  for (int nt = 0; nt < 8; ++nt) acc[nt] = (f32x4){0.f, 0.f, 0.f, 0.f};
  #pragma unroll
  for (int kk = 0; kk < 4; ++kk) {
    bf16x8 a = *(const bf16x8*)&Xs[arow * LP + kk * 32 + kb];
    #pragma unroll
    for (int nt = 0; nt < 8; ++nt) {
      bf16x8 b = *(const bf16x8*)&Ws[(nt * 16 + l15) * LP + kk * 32 + kb];
      acc[nt] = __builtin_amdgcn_mfma_f32_16x16x32_bf16(a, b, acc[nt], 0, 0, 0);
    }
  }
  const float* b1t = b1 + t * DIM;
  #pragma unroll
  for (int nt = 0; nt < 8; ++nt) {
    int col = nt * 16 + l15;
    float bias = b1t[col];
    #pragma unroll
    for (int r = 0; r < 4; ++r) {
      int row = w * 16 + q * 4 + r;     // wave-private rows: no cross-wave hazard
      Xs[row * LP + col] = f2bf(fmaxf(acc[nt][r] + bias, 0.f));
    }
  }
  __syncthreads();   // all Ws(W1) reads + H writes done

  // stage W2
  const unsigned short* w2g = W2t + (size_t)t * DIM * DIM;
  #pragma unroll
  for (int it = 0; it < 8; ++it) {
    int s = tid + it * 256;
    int n = s >> 4, c = s & 15;
    *(uint4*)&Ws[n * LP + c * 8] = *(const uint4*)(w2g + n * DIM + c * 8);
  }
  __syncthreads();

  // ---- layer 2: Y = H*W2 + b2 ----
  #pragma unroll
  for (int nt = 0; nt < 8; ++nt) acc[nt] = (f32x4){0.f, 0.f, 0.f, 0.f};
  #pragma unroll
  for (int kk = 0; kk < 4; ++kk) {
    bf16x8 a = *(const bf16x8*)&Xs[arow * LP + kk * 32 + kb];
    #pragma unroll
    for (int nt = 0; nt < 8; ++nt) {
      bf16x8 b = *(const bf16x8*)&Ws[(nt * 16 + l15) * LP + kk * 32 + kb];
      acc[nt] = __builtin_amdgcn_mfma_f32_16x16x32_bf16(a, b, acc[nt], 0, 0, 0);
    }
  }
  const float* b2t = b2 + t * DIM;
  int r0 = w * 16 + q * 4;
  int gr[4]; bool vld[4];
  #pragma unroll
  for (int r = 0; r < 4; ++r) {
    vld[r] = (r0 + r) < nvalid;
    gr[r] = prow[r0 + r];
  }
  #pragma unroll
  for (int nt = 0; nt < 8; ++nt) {
    int col = nt * 16 + l15;
    float bias = b2t[col];
    #pragma unroll
    for (int r = 0; r < 4; ++r) {
      if (vld[r]) out[(size_t)gr[r] * DIM + col] = acc[nt][r] + bias;
    }
  }
}

extern "C" void kernel_launch(void* const* d_in, const int* in_sizes, int n_in,
                              void* d_out, int out_size, void* d_ws, size_t ws_size,
                              hipStream_t stream) {
  const float* x  = (const float*)d_in[0];
  const float* W1 = (const float*)d_in[1];
  const float* b1 = (const float*)d_in[2];
  const float* W2 = (const float*)d_in[3];
  const float* b2 = (const float*)d_in[4];
  const int* types = (const int*)d_in[5];
  float* out = (float*)d_out;

  char* ws = (char*)d_ws;
  int* cnt = (int*)(ws + WS_CNT);
  unsigned short* rows = (unsigned short*)(ws + WS_ROWS);
  unsigned short* W1t  = (unsigned short*)(ws + WS_W1T);
  unsigned short* W2t  = (unsigned short*)(ws + WS_W2T);

  hipMemsetAsync(cnt, 0, NT * sizeof(int), stream);   // 68 B, graph-capturable
  k_pre<<<NB + 2 * NT, 256, 0, stream>>>(types, cnt, rows, W1, W2, W1t, W2t);
  dim3 grid(BPT, NT);
  k_mlp<<<grid, 256, 0, stream>>>(x, b1, b2, out, cnt, rows, W1t, W2t);
}